// Round 1
// baseline (1783.635 us; speedup 1.0000x reference)
//
#include <hip/hip_runtime.h>

// Problem constants (from reference): NC=64, C=256, D=32, K=16, K_b=16,
// ALPHA=16, B=16, H_S=H_M=128, H_MOD=32, N=16384, BS=8.
#define NCC   64
#define CCH   256
#define DD    32
#define KK    16
#define KBB   16
#define AL    16
#define BRD   16
#define HS    128
#define HM    128
#define NTOT  16384
#define BSZ   8
#define WSROW 68   // mod-out row (65) padded to multiple of 4 for aligned float4

// Unaligned-capable 16B load: mod_w1 rows are 113 floats (4B-aligned only).
// gfx950 global loads support unaligned access -> expect global_load_dwordx4.
struct __align__(4) F4u { float a0, a1, a2, a3; };
__device__ __forceinline__ F4u ld4u(const float* __restrict__ p) {
    return *reinterpret_cast<const F4u*>(p);
}
__device__ __forceinline__ float fsig(float v) { return 1.0f / (1.0f + __expf(-v)); }
__device__ __forceinline__ float ftanhf(float v) {
    // 1 - 2/(e^{2x}+1): saturates correctly at +/-1 for large |x| (no inf/inf)
    return 1.0f - 2.0f / (__expf(2.0f * v) + 1.0f);
}

// ---------------------------------------------------------------------------
// Kernel A: per-neuron "mod" MLP. 4 neurons per block, 256 threads.
//   hid = tanh(mod_w1 @ flat + b1)  (32x113)
//   out = hid @ mod_w2 + b2         (32x65) -> ws rows padded to 68
// Memory-bound on the 380MB weight stream; weights read straight from global
// (8-way lane duplication merges in the coalescer), inputs staged in LDS once.
// ---------------------------------------------------------------------------
__global__ __launch_bounds__(256) void kA(
    const float* __restrict__ x, const float* __restrict__ h_in,
    const float* __restrict__ dlog, const float* __restrict__ prim,
    const float* __restrict__ heb, const float* __restrict__ nidp,
    const float* __restrict__ mw1, const float* __restrict__ mb1,
    const float* __restrict__ mw2, const float* __restrict__ mb2,
    float* __restrict__ outw)
{
    __shared__ __align__(16) float s_flat[4][8][116]; // 113 inputs + 3 zero pad
    __shared__ __align__(16) float s_hid[4][8][32];

    const int tid = threadIdx.x;
    const int n0  = blockIdx.x * 4;
    const int nc  = n0 >> 8;
    const int c0  = n0 & 255;

    // ---- phase 0: build mod_input = [heb(16), h+inj(32), decay(1), prim(32), nid(32)]
    for (int e = tid; e < 4 * 8 * 116; e += 256) {
        const int cc = e / (8 * 116);
        const int rr = e - cc * (8 * 116);
        const int b  = rr / 116;
        const int i  = rr - b * 116;
        const int c  = c0 + cc;
        const int row = (b * NCC + nc) * CCH + c;
        float v;
        if (i < 16)        v = heb[(size_t)row * KK + i];
        else if (i < 48) { const int d = i - 16;
                           v = h_in[(size_t)row * DD + d]
                             + (c < AL ? x[(size_t)(b * NCC + nc) * DD + d] : 0.0f); }
        else if (i == 48)  v = dlog[row];
        else if (i < 81)   v = prim[(size_t)row * DD + (i - 49)];
        else if (i < 113)  v = nidp[(size_t)(nc * CCH + c) * DD + (i - 81)];
        else               v = 0.0f;
        s_flat[cc][b][i] = v;
    }
    __syncthreads();

    const int cc = tid >> 6;
    const int b  = (tid >> 3) & 7;
    const int n  = n0 + cc;

    // ---- phase 1: hid (thread = (cc,b,hg), 4 hidden rows each)
    {
        const int hg = tid & 7;
        const float* __restrict__ w1 = mw1 + (size_t)n * (32 * 113);
        const float* xr = &s_flat[cc][b][0];
        float acc0 = mb1[n * 32 + hg];
        float acc1 = mb1[n * 32 + hg + 8];
        float acc2 = mb1[n * 32 + hg + 16];
        float acc3 = mb1[n * 32 + hg + 24];
        #pragma unroll
        for (int i = 0; i < 112; i += 4) {
            float4 xv = *(const float4*)(xr + i);
            F4u w0 = ld4u(w1 + (hg     ) * 113 + i);
            F4u wa = ld4u(w1 + (hg +  8) * 113 + i);
            F4u wb = ld4u(w1 + (hg + 16) * 113 + i);
            F4u wc = ld4u(w1 + (hg + 24) * 113 + i);
            acc0 += w0.a0*xv.x + w0.a1*xv.y + w0.a2*xv.z + w0.a3*xv.w;
            acc1 += wa.a0*xv.x + wa.a1*xv.y + wa.a2*xv.z + wa.a3*xv.w;
            acc2 += wb.a0*xv.x + wb.a1*xv.y + wb.a2*xv.z + wb.a3*xv.w;
            acc3 += wc.a0*xv.x + wc.a1*xv.y + wc.a2*xv.z + wc.a3*xv.w;
        }
        const float xt = xr[112];
        acc0 += w1[(hg     ) * 113 + 112] * xt;
        acc1 += w1[(hg +  8) * 113 + 112] * xt;
        acc2 += w1[(hg + 16) * 113 + 112] * xt;
        acc3 += w1[(hg + 24) * 113 + 112] * xt;
        s_hid[cc][b][hg     ] = ftanhf(acc0);
        s_hid[cc][b][hg +  8] = ftanhf(acc1);
        s_hid[cc][b][hg + 16] = ftanhf(acc2);
        s_hid[cc][b][hg + 24] = ftanhf(acc3);
    }
    __syncthreads();

    // ---- phase 2: out (thread = (cc,b,og), 8 outputs each; o=64 via all lanes, og==7 stores)
    {
        const int og = tid & 7;
        const float* __restrict__ w2 = mw2 + (size_t)n * (32 * 65);
        float hv[32];
        #pragma unroll
        for (int q = 0; q < 8; ++q) {
            float4 t = *(const float4*)&s_hid[cc][b][q * 4];
            hv[q*4+0]=t.x; hv[q*4+1]=t.y; hv[q*4+2]=t.z; hv[q*4+3]=t.w;
        }
        float acc[8];
        #pragma unroll
        for (int j = 0; j < 8; ++j) acc[j] = mb2[n * 65 + og * 8 + j];
        float acc8 = mb2[n * 65 + 64];
        #pragma unroll
        for (int hh = 0; hh < 32; ++hh) {
            const float* wr = w2 + hh * 65;
            F4u wA = ld4u(wr + og * 8);
            F4u wB = ld4u(wr + og * 8 + 4);
            const float hvv = hv[hh];
            acc[0] += hvv * wA.a0; acc[1] += hvv * wA.a1;
            acc[2] += hvv * wA.a2; acc[3] += hvv * wA.a3;
            acc[4] += hvv * wB.a0; acc[5] += hvv * wB.a1;
            acc[6] += hvv * wB.a2; acc[7] += hvv * wB.a3;
            acc8   += hvv * wr[64];          // wave-uniform -> s_load
        }
        float* orow = outw + ((size_t)b * NTOT + n) * WSROW;
        *(float4*)(orow + og * 8)     = make_float4(acc[0], acc[1], acc[2], acc[3]);
        *(float4*)(orow + og * 8 + 4) = make_float4(acc[4], acc[5], acc[6], acc[7]);
        if (og == 7) orow[64] = acc8;
    }
}

// ---------------------------------------------------------------------------
// Kernel B: everything else. 1 thread = one (b, nc, c) row, fully in registers.
// Shared-weight MLPs use wave-uniform weight addresses -> scalar (s_load) path,
// inputs in VGPRs -> full-rate v_fmac, no LDS.
// ---------------------------------------------------------------------------
__global__ __launch_bounds__(256) void kB(
    const float* __restrict__ x, const float* __restrict__ h_in,
    const float* __restrict__ prev, const float* __restrict__ heb_in,
    const float* __restrict__ hebb_in,
    const float* __restrict__ sw1, const float* __restrict__ sb1,
    const float* __restrict__ sw2, const float* __restrict__ sb2,
    const float* __restrict__ qw1, const float* __restrict__ qb1,
    const float* __restrict__ qw2, const float* __restrict__ qb2,
    const float* __restrict__ nidp,
    const int* __restrict__ conn, const int* __restrict__ bconn,
    const float* __restrict__ outw,
    float* __restrict__ o_hnew, float* __restrict__ o_msg,
    float* __restrict__ o_heb, float* __restrict__ o_hebb)
{
    const int r  = blockIdx.x * 256 + threadIdx.x;   // r = b*16384 + n
    const int b  = r >> 14;
    const int n  = r & (NTOT - 1);
    const int nc = n >> 8;
    const int c  = n & 255;
    const int cellbase = (b * NCC + nc) * CCH;       // cellbase + c == r

    // mod outputs (65 used, 68-row in ws)
    float ov[68];
    {
        const float4* op = (const float4*)(outw + (size_t)r * WSROW);
        #pragma unroll
        for (int q = 0; q < 17; ++q) {
            float4 t = op[q];
            ov[q*4+0]=t.x; ov[q*4+1]=t.y; ov[q*4+2]=t.z; ov[q*4+3]=t.w;
        }
    }
    // h (+ injection for c < ALPHA)
    float hv[32];
    {
        const float4* hp = (const float4*)(h_in + (size_t)r * DD);
        #pragma unroll
        for (int q = 0; q < 8; ++q) {
            float4 t = hp[q];
            hv[q*4+0]=t.x; hv[q*4+1]=t.y; hv[q*4+2]=t.z; hv[q*4+3]=t.w;
        }
        if (c < AL) {
            const float4* xp = (const float4*)(x + (size_t)(b * NCC + nc) * DD);
            #pragma unroll
            for (int q = 0; q < 8; ++q) {
                float4 t = xp[q];
                hv[q*4+0]+=t.x; hv[q*4+1]+=t.y; hv[q*4+2]+=t.z; hv[q*4+3]+=t.w;
            }
        }
    }
    // hebbian traces
    float hb[16];
    {
        const float4* ep = (const float4*)(heb_in + (size_t)r * KK);
        #pragma unroll
        for (int q = 0; q < 4; ++q) {
            float4 t = ep[q];
            hb[q*4+0]=t.x; hb[q*4+1]=t.y; hb[q*4+2]=t.z; hb[q*4+3]=t.w;
        }
    }
    // ---- aggregation over K neighbors (gather from prev_messages, L2-hot)
    float agg[32];
    #pragma unroll
    for (int d = 0; d < 32; ++d) agg[d] = 0.0f;
    {
        const int4* cp = (const int4*)(conn + n * KK);
        #pragma unroll
        for (int q = 0; q < 4; ++q) {
            int4 ci = cp[q];
            int cis[4] = {ci.x, ci.y, ci.z, ci.w};
            #pragma unroll
            for (int kk = 0; kk < 4; ++kk) {
                const int k = q * 4 + kk;
                const float wk = fsig(ov[k] + hb[k]);
                const float4* np = (const float4*)(prev + (size_t)(cellbase + cis[kk]) * DD);
                #pragma unroll
                for (int dq = 0; dq < 8; ++dq) {
                    float4 t = np[dq];
                    agg[dq*4+0] += wk*t.x; agg[dq*4+1] += wk*t.y;
                    agg[dq*4+2] += wk*t.z; agg[dq*4+3] += wk*t.w;
                }
            }
        }
    }
    const bool isb = (c >= AL) && (c < AL + BRD);
    if (isb) {  // border aggregation (channels 16..31)
        const int cb = c - AL;
        const int4*   bp  = (const int4*)(bconn + (nc * BRD + cb) * KBB);
        const float4* hp4 = (const float4*)(hebb_in + (size_t)((b * NCC + nc) * BRD + cb) * KBB);
        #pragma unroll
        for (int q = 0; q < 4; ++q) {
            int4 bi = bp[q];
            float4 hbt = hp4[q];
            int bis[4]   = {bi.x, bi.y, bi.z, bi.w};
            float hbs[4] = {hbt.x, hbt.y, hbt.z, hbt.w};
            #pragma unroll
            for (int kk = 0; kk < 4; ++kk) {
                const int k   = q * 4 + kk;
                const int idx = bis[kk];
                const int nb  = idx >> 4;
                const int ch  = AL + (idx & 15);
                const float wk = fsig(ov[16 + k] + hbs[kk]);
                const float4* np = (const float4*)(prev + (size_t)((b * NCC + nb) * CCH + ch) * DD);
                #pragma unroll
                for (int dq = 0; dq < 8; ++dq) {
                    float4 t = np[dq];
                    agg[dq*4+0] += wk*t.x; agg[dq*4+1] += wk*t.y;
                    agg[dq*4+2] += wk*t.z; agg[dq*4+3] += wk*t.w;
                }
            }
        }
    }

    // ---- state MLP: sin = [h(32), agg(32), new_prim(32)=ov[33..64], new_decay=ov[32]]
    float delta[32];
    #pragma unroll
    for (int d = 0; d < 32; ++d) delta[d] = sb2[d];
    #pragma unroll 1
    for (int hc = 0; hc < 16; ++hc) {       // 8 hidden units per chunk (code-size control)
        float sh[8];
        #pragma unroll
        for (int jj = 0; jj < 8; ++jj) {
            const int hh = hc * 8 + jj;
            const float* __restrict__ wr = sw1 + hh * 97;   // uniform address -> s_load
            float a = sb1[hh];
            #pragma unroll
            for (int i = 0; i < 32; ++i) a += wr[i]      * hv[i];
            #pragma unroll
            for (int i = 0; i < 32; ++i) a += wr[32 + i] * agg[i];
            #pragma unroll
            for (int i = 0; i < 32; ++i) a += wr[64 + i] * ov[33 + i];
            a += wr[96] * ov[32];
            sh[jj] = ftanhf(a);
        }
        #pragma unroll
        for (int d = 0; d < 32; ++d) {
            const float* __restrict__ w2r = sw2 + d * HS + hc * 8;
            float a = delta[d];
            #pragma unroll
            for (int jj = 0; jj < 8; ++jj) a += w2r[jj] * sh[jj];
            delta[d] = a;
        }
    }
    // ---- h_new
    const float sd = fsig(ov[32]);
    float hnew[32];
    #pragma unroll
    for (int d = 0; d < 32; ++d) hnew[d] = sd * hv[d] + (1.0f - sd) * ftanhf(delta[d]);
    {
        float4* hop = (float4*)(o_hnew + (size_t)r * DD);
        #pragma unroll
        for (int q = 0; q < 8; ++q)
            hop[q] = make_float4(hnew[q*4+0], hnew[q*4+1], hnew[q*4+2], hnew[q*4+3]);
    }
    // neuron id
    float nv[32];
    {
        const float4* npd = (const float4*)(nidp + (size_t)n * DD);
        #pragma unroll
        for (int q = 0; q < 8; ++q) {
            float4 t = npd[q];
            nv[q*4+0]=t.x; nv[q*4+1]=t.y; nv[q*4+2]=t.z; nv[q*4+3]=t.w;
        }
    }
    // ---- msg MLP: min = [h_new(32), agg(32), nid(32)]
    float macc[32];
    #pragma unroll
    for (int d = 0; d < 32; ++d) macc[d] = qb2[d];
    #pragma unroll 1
    for (int hc = 0; hc < 16; ++hc) {
        float sh[8];
        #pragma unroll
        for (int jj = 0; jj < 8; ++jj) {
            const int hh = hc * 8 + jj;
            const float* __restrict__ wr = qw1 + hh * 96;
            float a = qb1[hh];
            #pragma unroll
            for (int i = 0; i < 32; ++i) a += wr[i]      * hnew[i];
            #pragma unroll
            for (int i = 0; i < 32; ++i) a += wr[32 + i] * agg[i];
            #pragma unroll
            for (int i = 0; i < 32; ++i) a += wr[64 + i] * nv[i];
            sh[jj] = ftanhf(a);
        }
        #pragma unroll
        for (int d = 0; d < 32; ++d) {
            const float* __restrict__ w2r = qw2 + d * HM + hc * 8;
            float a = macc[d];
            #pragma unroll
            for (int jj = 0; jj < 8; ++jj) a += w2r[jj] * sh[jj];
            macc[d] = a;
        }
    }
    {
        float4* mop = (float4*)(o_msg + (size_t)r * DD);
        #pragma unroll
        for (int q = 0; q < 8; ++q)
            mop[q] = make_float4(macc[q*4+0], macc[q*4+1], macc[q*4+2], macc[q*4+3]);
    }
    // ---- hebbian update: heb = 0.9*heb + (0.1/32) * msg . neigh
    {
        const int4* cp = (const int4*)(conn + n * KK);
        #pragma unroll
        for (int q = 0; q < 4; ++q) {
            int4 ci = cp[q];
            int cis[4] = {ci.x, ci.y, ci.z, ci.w};
            float hres[4];
            #pragma unroll
            for (int kk = 0; kk < 4; ++kk) {
                const float4* np = (const float4*)(prev + (size_t)(cellbase + cis[kk]) * DD);
                float dot = 0.0f;
                #pragma unroll
                for (int dq = 0; dq < 8; ++dq) {
                    float4 t = np[dq];
                    dot += macc[dq*4+0]*t.x + macc[dq*4+1]*t.y
                         + macc[dq*4+2]*t.z + macc[dq*4+3]*t.w;
                }
                hres[kk] = 0.9f * hb[q*4+kk] + 0.003125f * dot;   // 0.1/32
            }
            *(float4*)(o_heb + (size_t)r * KK + q*4)
                = make_float4(hres[0], hres[1], hres[2], hres[3]);
        }
    }
    if (isb) {  // border hebbian update
        const int cb = c - AL;
        const int4*   bp  = (const int4*)(bconn + (nc * BRD + cb) * KBB);
        const float4* hp4 = (const float4*)(hebb_in + (size_t)((b * NCC + nc) * BRD + cb) * KBB);
        #pragma unroll
        for (int q = 0; q < 4; ++q) {
            int4 bi = bp[q];
            float4 hbt = hp4[q];
            int bis[4]   = {bi.x, bi.y, bi.z, bi.w};
            float hbs[4] = {hbt.x, hbt.y, hbt.z, hbt.w};
            float hres[4];
            #pragma unroll
            for (int kk = 0; kk < 4; ++kk) {
                const int idx = bis[kk];
                const int nb  = idx >> 4;
                const int ch  = AL + (idx & 15);
                const float4* np = (const float4*)(prev + (size_t)((b * NCC + nb) * CCH + ch) * DD);
                float dot = 0.0f;
                #pragma unroll
                for (int dq = 0; dq < 8; ++dq) {
                    float4 t = np[dq];
                    dot += macc[dq*4+0]*t.x + macc[dq*4+1]*t.y
                         + macc[dq*4+2]*t.z + macc[dq*4+3]*t.w;
                }
                hres[kk] = 0.9f * hbs[kk] + 0.003125f * dot;
            }
            *(float4*)(o_hebb + (size_t)((b * NCC + nc) * BRD + cb) * KBB + q*4)
                = make_float4(hres[0], hres[1], hres[2], hres[3]);
        }
    }
}

// ---------------------------------------------------------------------------
// Kernel C: readout = mean over channels [C-ALPHA, C) of msg  -> (BS, NC*D)
// ---------------------------------------------------------------------------
__global__ __launch_bounds__(256) void kC(const float* __restrict__ msg,
                                          float* __restrict__ ro)
{
    const int t = blockIdx.x * 256 + threadIdx.x;   // 16384 total
    const int b   = t >> 11;
    const int rem = t & 2047;
    const int nc  = rem >> 5;
    const int d   = rem & 31;
    const float* mp = msg + (size_t)((b * NCC + nc) * CCH + (CCH - AL)) * DD + d;
    float s = 0.0f;
    #pragma unroll
    for (int j = 0; j < 16; ++j) s += mp[j * DD];
    ro[t] = s * (1.0f / 16.0f);
}

extern "C" void kernel_launch(void* const* d_in, const int* in_sizes, int n_in,
                              void* d_out, int out_size, void* d_ws, size_t ws_size,
                              hipStream_t stream) {
    const float* x     = (const float*)d_in[0];
    const float* h     = (const float*)d_in[1];
    const float* prev  = (const float*)d_in[2];
    const float* dlog  = (const float*)d_in[3];
    const float* prim  = (const float*)d_in[4];
    const float* heb   = (const float*)d_in[5];
    const float* hebb  = (const float*)d_in[6];
    const float* sw1   = (const float*)d_in[7];
    const float* sb1   = (const float*)d_in[8];
    const float* sw2   = (const float*)d_in[9];
    const float* sb2   = (const float*)d_in[10];
    const float* qw1   = (const float*)d_in[11];  // msg_w1
    const float* qb1   = (const float*)d_in[12];
    const float* qw2   = (const float*)d_in[13];
    const float* qb2   = (const float*)d_in[14];
    const float* mw1   = (const float*)d_in[15];  // mod_w1
    const float* mb1   = (const float*)d_in[16];
    const float* mw2   = (const float*)d_in[17];
    const float* mb2   = (const float*)d_in[18];
    const float* nid   = (const float*)d_in[19];
    const int*   conn  = (const int*)d_in[20];
    const int*   bconn = (const int*)d_in[21];

    float* out   = (float*)d_out;
    float* ro    = out;                          // (8, 2048)
    float* hnew  = out + 16384;                  // (8,64,256,32)
    float* msg   = hnew + 4194304;               // (8,64,256,32)
    float* hebo  = msg + 4194304;                // (8,64,256,16)
    float* hebbo = hebo + 2097152;               // (8,64,16,16)
    float* ws    = (float*)d_ws;                 // needs 8*16384*68*4 = 35,651,584 B

    kA<<<NTOT / 4, 256, 0, stream>>>(x, h, dlog, prim, heb, nid, mw1, mb1, mw2, mb2, ws);
    kB<<<(BSZ * NTOT) / 256, 256, 0, stream>>>(x, h, prev, heb, hebb,
                                               sw1, sb1, sw2, sb2,
                                               qw1, qb1, qw2, qb2,
                                               nid, conn, bconn, ws,
                                               hnew, msg, hebo, hebbo);
    kC<<<64, 256, 0, stream>>>(msg, ro);
}

// Round 3
// 1024.188 us; speedup vs baseline: 1.7415x; 1.7415x over previous
//
#include <hip/hip_runtime.h>

// NC=64, C=256, D=32, K=16, K_b=16, ALPHA=16, B=16, H_S=H_M=128, H_MOD=32,
// N=16384, BS=8.
#define NCC   64
#define CCH   256
#define DD    32
#define KK    16
#define KBB   16
#define AL    16
#define BRD   16
#define NTOT  16384
#define BSZ   8
#define WSROW 68

#ifndef __has_builtin
#define __has_builtin(x) 0
#endif
#if __has_builtin(__builtin_amdgcn_fdot2)
#define HAVE_FDOT2 1
#else
#define HAVE_FDOT2 0
#endif

typedef unsigned int uint32;
// NOTE: clang's amdgcn builtins use __fp16 vectors (not _Float16): cvt_pkrtz
// returns v2 __fp16 and fdot2 consumes it. Round-2 compile failure was this.
typedef __fp16 half2v __attribute__((ext_vector_type(2)));
union HU { half2v h; uint32 u; };

struct __align__(4) F4u { float a0, a1, a2, a3; };
struct __align__(4) F2u { float a, b; };
__device__ __forceinline__ F4u ld4u(const float* __restrict__ p) {
    return *reinterpret_cast<const F4u*>(p);
}
__device__ __forceinline__ float fsig(float v) { return 1.0f / (1.0f + __expf(-v)); }
__device__ __forceinline__ float ftanhf(float v) {
    return 1.0f - 2.0f / (__expf(2.0f * v) + 1.0f);
}
__device__ __forceinline__ uint32 packpair(float a, float b) {
    HU cv; cv.h = __builtin_amdgcn_cvt_pkrtz(a, b);
    return cv.u;
}
__device__ __forceinline__ void unpackpair(uint32 u, float& a, float& b) {
    HU cv; cv.u = u;
    a = (float)cv.h.x; b = (float)cv.h.y;
}
__device__ __forceinline__ float dot2(uint32 x, uint32 w, float c) {
    HU a, b; a.u = x; b.u = w;
#if HAVE_FDOT2
    return __builtin_amdgcn_fdot2(a.h, b.h, c, false);
#else
    return c + (float)a.h.x * (float)b.h.x + (float)a.h.y * (float)b.h.y;
#endif
}

// ---------------------------------------------------------------------------
// Kernel A: per-neuron mod MLP. Block = 8 neurons, 256 threads.
// Phase 1: thread=(neuron nl, hidden h); each lane streams its OWN contiguous
// w1 row from global (1KB distinct bytes per wave-instr), inputs broadcast
// from LDS. Phase 2: thread=(nl, o2) computes outputs 2*o2, 2*o2+1; w2 read
// coalesced 8B/lane.
// ---------------------------------------------------------------------------
__global__ __launch_bounds__(256) void kA(
    const float* __restrict__ x, const float* __restrict__ h_in,
    const float* __restrict__ dlog, const float* __restrict__ prim,
    const float* __restrict__ heb, const float* __restrict__ nidp,
    const float* __restrict__ mw1, const float* __restrict__ mb1,
    const float* __restrict__ mw2, const float* __restrict__ mb2,
    float* __restrict__ outw)
{
    __shared__ __align__(16) float s_flat[8][8][116]; // [neuron][batch][113+pad]
    __shared__ __align__(16) float s_hid[8][32][8];   // [neuron][h][batch]

    const int tid = threadIdx.x;
    const int n0  = blockIdx.x * 8;
    const int nc  = n0 >> 8;
    const int c0  = n0 & 255;

    // phase 0: mod_input = [heb(16), h+inj(32), decay(1), prim(32), nid(32)]
    for (int e = tid; e < 8 * 8 * 116; e += 256) {
        const int nl = e / (8 * 116);
        const int rr = e - nl * (8 * 116);
        const int b  = rr / 116;
        const int i  = rr - b * 116;
        const int c  = c0 + nl;
        const int row = (b * NCC + nc) * CCH + c;
        float v;
        if (i < 16)        v = heb[(size_t)row * KK + i];
        else if (i < 48) { const int d = i - 16;
                           v = h_in[(size_t)row * DD + d]
                             + (c < AL ? x[(size_t)(b * NCC + nc) * DD + d] : 0.0f); }
        else if (i == 48)  v = dlog[row];
        else if (i < 81)   v = prim[(size_t)row * DD + (i - 49)];
        else if (i < 113)  v = nidp[(size_t)(nc * CCH + c) * DD + (i - 81)];
        else               v = 0.0f;
        s_flat[nl][b][i] = v;
    }
    __syncthreads();

    const int nl = tid >> 5;
    const int n  = n0 + nl;

    // ---- phase 1: hid[h][b] = tanh(w1[h,:] . flat[b,:] + b1[h])
    {
        const int h = tid & 31;
        const float* __restrict__ w1row = mw1 + ((size_t)n * 32 + h) * 113;
        const float bias = mb1[n * 32 + h];
        float acc[8];
        #pragma unroll
        for (int b = 0; b < 8; ++b) acc[b] = bias;
        #pragma unroll
        for (int i = 0; i < 112; i += 4) {
            F4u w = ld4u(w1row + i);
            #pragma unroll
            for (int b = 0; b < 8; ++b) {
                float4 xv = *(const float4*)&s_flat[nl][b][i];
                acc[b] += w.a0*xv.x + w.a1*xv.y + w.a2*xv.z + w.a3*xv.w;
            }
        }
        const float wt = w1row[112];
        #pragma unroll
        for (int b = 0; b < 8; ++b) acc[b] += wt * s_flat[nl][b][112];
        float4 t0 = make_float4(ftanhf(acc[0]), ftanhf(acc[1]), ftanhf(acc[2]), ftanhf(acc[3]));
        float4 t1 = make_float4(ftanhf(acc[4]), ftanhf(acc[5]), ftanhf(acc[6]), ftanhf(acc[7]));
        *(float4*)&s_hid[nl][h][0] = t0;
        *(float4*)&s_hid[nl][h][4] = t1;
    }
    __syncthreads();

    // ---- phase 2: out[b][o] = hid[b,:] . w2[:,o] + b2[o];  o = 2*o2, 2*o2+1
    {
        const int o2 = tid & 31;
        const float* __restrict__ w2base = mw2 + (size_t)n * (32 * 65);
        float acc0[8], acc1[8];
        {
            const float bz0 = mb2[n * 65 + 2 * o2];
            const float bz1 = mb2[n * 65 + 2 * o2 + 1];
            #pragma unroll
            for (int b = 0; b < 8; ++b) { acc0[b] = bz0; acc1[b] = bz1; }
        }
        #pragma unroll 4
        for (int hh = 0; hh < 32; ++hh) {
            F2u w = *(const F2u*)(w2base + hh * 65 + 2 * o2);  // coalesced 8B/lane
            float4 hA = *(const float4*)&s_hid[nl][hh][0];
            float4 hB = *(const float4*)&s_hid[nl][hh][4];
            acc0[0] += w.a*hA.x; acc0[1] += w.a*hA.y; acc0[2] += w.a*hA.z; acc0[3] += w.a*hA.w;
            acc0[4] += w.a*hB.x; acc0[5] += w.a*hB.y; acc0[6] += w.a*hB.z; acc0[7] += w.a*hB.w;
            acc1[0] += w.b*hA.x; acc1[1] += w.b*hA.y; acc1[2] += w.b*hA.z; acc1[3] += w.b*hA.w;
            acc1[4] += w.b*hB.x; acc1[5] += w.b*hB.y; acc1[6] += w.b*hB.z; acc1[7] += w.b*hB.w;
        }
        #pragma unroll
        for (int b = 0; b < 8; ++b) {
            float* row = outw + ((size_t)b * NTOT + n) * WSROW;
            *(float2*)(row + 2 * o2) = make_float2(acc0[b], acc1[b]);
        }
        if (o2 == 31) {  // 65th output column
            float a64[8];
            const float bz = mb2[n * 65 + 64];
            #pragma unroll
            for (int b = 0; b < 8; ++b) a64[b] = bz;
            for (int hh = 0; hh < 32; ++hh) {
                const float wv = w2base[hh * 65 + 64];
                float4 hA = *(const float4*)&s_hid[nl][hh][0];
                float4 hB = *(const float4*)&s_hid[nl][hh][4];
                a64[0] += wv*hA.x; a64[1] += wv*hA.y; a64[2] += wv*hA.z; a64[3] += wv*hA.w;
                a64[4] += wv*hB.x; a64[5] += wv*hB.y; a64[6] += wv*hB.z; a64[7] += wv*hB.w;
            }
            #pragma unroll
            for (int b = 0; b < 8; ++b)
                outw[((size_t)b * NTOT + n) * WSROW + 64] = a64[b];
        }
    }
}

// ---------------------------------------------------------------------------
// Kernel B helpers: stage one MLP's weights into LDS as packed f16 pairs.
// w1buf[h][p] = input pair (2p,2p+1) of the zero-padded-104 input vector;
// w2buf[d][p] = hidden pair (2p,2p+1) over the 128 hiddens.
// ---------------------------------------------------------------------------
__device__ __forceinline__ void stageW(int tid, const float* __restrict__ w1g, int n1,
                                       const float* __restrict__ b1g,
                                       const float* __restrict__ w2g,
                                       const float* __restrict__ b2g,
                                       uint32 (*w1buf)[52], uint32 (*w2buf)[64],
                                       float* b1buf, float* b2buf)
{
    for (int t = tid; t < 128 * 52; t += 256) {
        const int hh = t / 52;
        const int p  = t - hh * 52;
        const int e0 = 2 * p, e1 = 2 * p + 1;
        const float f0 = (e0 < n1) ? w1g[hh * n1 + e0] : 0.0f;
        const float f1 = (e1 < n1) ? w1g[hh * n1 + e1] : 0.0f;
        w1buf[hh][p] = packpair(f0, f1);
    }
    for (int t = tid; t < 32 * 64; t += 256) {
        const int d = t >> 6;
        const int p = t & 63;
        w2buf[d][p] = packpair(w2g[d * 128 + 2 * p], w2g[d * 128 + 2 * p + 1]);
    }
    if (tid < 128) b1buf[tid] = b1g[tid];
    if (tid < 32)  b2buf[tid] = b2g[tid];
}

// xin: 52 packed half2 pairs. out[32] = layer2(tanh(layer1(xin) + b1)) + b2.
__device__ __forceinline__ void mlp2(const uint32* xin,
                                     const uint32 (*w1)[52], const uint32 (*w2)[64],
                                     const float* b1, const float* b2, float* out)
{
    #pragma unroll
    for (int d = 0; d < 32; ++d) out[d] = b2[d];
    #pragma unroll 1
    for (int hc = 0; hc < 16; ++hc) {
        float sh[8];
        #pragma unroll
        for (int jj = 0; jj < 8; ++jj) {
            const int h = hc * 8 + jj;
            float a = b1[h];
            #pragma unroll
            for (int p = 0; p < 13; ++p) {
                uint4 wq = *(const uint4*)&w1[h][p * 4];   // ds_read_b128 broadcast
                a = dot2(xin[p*4+0], wq.x, a);
                a = dot2(xin[p*4+1], wq.y, a);
                a = dot2(xin[p*4+2], wq.z, a);
                a = dot2(xin[p*4+3], wq.w, a);
            }
            sh[jj] = ftanhf(a);
        }
        uint32 shp[4];
        #pragma unroll
        for (int q = 0; q < 4; ++q) shp[q] = packpair(sh[2*q], sh[2*q+1]);
        #pragma unroll
        for (int d = 0; d < 32; ++d) {
            uint4 wq = *(const uint4*)&w2[d][hc * 4];
            float a = out[d];
            a = dot2(shp[0], wq.x, a);
            a = dot2(shp[1], wq.y, a);
            a = dot2(shp[2], wq.z, a);
            a = dot2(shp[3], wq.w, a);
            out[d] = a;
        }
    }
}

// ---------------------------------------------------------------------------
// Kernel B: thread = one (b,nc,c) row. Shared MLP weights live in LDS as f16,
// consumed with v_dot2_f32_f16 (f32 accumulate). Two staging phases:
// state weights, then msg weights.
// ---------------------------------------------------------------------------
__global__ __launch_bounds__(256) void kB(
    const float* __restrict__ x, const float* __restrict__ h_in,
    const float* __restrict__ prev, const float* __restrict__ heb_in,
    const float* __restrict__ hebb_in,
    const float* __restrict__ sw1, const float* __restrict__ sb1,
    const float* __restrict__ sw2, const float* __restrict__ sb2,
    const float* __restrict__ qw1, const float* __restrict__ qb1,
    const float* __restrict__ qw2, const float* __restrict__ qb2,
    const float* __restrict__ nidp,
    const int* __restrict__ conn, const int* __restrict__ bconn,
    const float* __restrict__ wsm,
    float* __restrict__ o_hnew, float* __restrict__ o_msg,
    float* __restrict__ o_heb, float* __restrict__ o_hebb)
{
    __shared__ __align__(16) uint32 w1buf[128][52];
    __shared__ __align__(16) uint32 w2buf[32][64];
    __shared__ float b1buf[128];
    __shared__ float b2buf[32];

    const int tid = threadIdx.x;
    const int r  = blockIdx.x * 256 + tid;
    const int b  = r >> 14;
    const int n  = r & (NTOT - 1);
    const int nc = n >> 8;
    const int c  = n & 255;
    const int cellbase = (b * NCC + nc) * CCH;

    stageW(tid, sw1, 97, sb1, sw2, sb2, w1buf, w2buf, b1buf, b2buf);
    __syncthreads();

    // ---- mod outputs: w_conn(16), border w(16), decay + prim -> xs[32..48]
    float ovw[16], ovb[16], decayl;
    uint32 xs[52];
    {
        const float4* op4 = (const float4*)(wsm + (size_t)r * WSROW);
        #pragma unroll
        for (int q = 0; q < 4; ++q) {
            float4 t = op4[q];
            ovw[q*4+0]=t.x; ovw[q*4+1]=t.y; ovw[q*4+2]=t.z; ovw[q*4+3]=t.w;
        }
        #pragma unroll
        for (int q = 0; q < 4; ++q) {
            float4 t = op4[4 + q];
            ovb[q*4+0]=t.x; ovb[q*4+1]=t.y; ovb[q*4+2]=t.z; ovb[q*4+3]=t.w;
        }
        float tail[36];
        #pragma unroll
        for (int q = 0; q < 9; ++q) {
            float4 t = op4[8 + q];
            tail[q*4+0]=t.x; tail[q*4+1]=t.y; tail[q*4+2]=t.z; tail[q*4+3]=t.w;
        }
        decayl = tail[0];
        #pragma unroll
        for (int q = 0; q < 16; ++q)
            xs[32 + q] = packpair(tail[1 + 2*q], tail[2 + 2*q]);   // new_prim
        xs[48] = packpair(decayl, 0.0f);
        xs[49] = xs[50] = xs[51] = 0u;
    }
    // ---- h (+ injection) -> xs[0..15]
    {
        float hvf[32];
        const float4* hp = (const float4*)(h_in + (size_t)r * DD);
        #pragma unroll
        for (int q = 0; q < 8; ++q) {
            float4 t = hp[q];
            hvf[q*4+0]=t.x; hvf[q*4+1]=t.y; hvf[q*4+2]=t.z; hvf[q*4+3]=t.w;
        }
        if (c < AL) {
            const float4* xp = (const float4*)(x + (size_t)(b * NCC + nc) * DD);
            #pragma unroll
            for (int q = 0; q < 8; ++q) {
                float4 t = xp[q];
                hvf[q*4+0]+=t.x; hvf[q*4+1]+=t.y; hvf[q*4+2]+=t.z; hvf[q*4+3]+=t.w;
            }
        }
        #pragma unroll
        for (int q = 0; q < 16; ++q) xs[q] = packpair(hvf[2*q], hvf[2*q+1]);
    }
    // ---- hebbian traces (kept for heb update)
    float hb[16];
    {
        const float4* ep = (const float4*)(heb_in + (size_t)r * KK);
        #pragma unroll
        for (int q = 0; q < 4; ++q) {
            float4 t = ep[q];
            hb[q*4+0]=t.x; hb[q*4+1]=t.y; hb[q*4+2]=t.z; hb[q*4+3]=t.w;
        }
    }
    const bool isb = (c >= AL) && (c < AL + BRD);
    // ---- aggregation -> xs[16..31]
    {
        float agg[32];
        #pragma unroll
        for (int d = 0; d < 32; ++d) agg[d] = 0.0f;
        const int4* cp = (const int4*)(conn + n * KK);
        #pragma unroll
        for (int q = 0; q < 4; ++q) {
            int4 ci = cp[q];
            int cis[4] = {ci.x, ci.y, ci.z, ci.w};
            #pragma unroll
            for (int kk = 0; kk < 4; ++kk) {
                const int k = q * 4 + kk;
                const float wk = fsig(ovw[k] + hb[k]);
                const float4* np = (const float4*)(prev + (size_t)(cellbase + cis[kk]) * DD);
                #pragma unroll
                for (int dq = 0; dq < 8; ++dq) {
                    float4 t = np[dq];
                    agg[dq*4+0] += wk*t.x; agg[dq*4+1] += wk*t.y;
                    agg[dq*4+2] += wk*t.z; agg[dq*4+3] += wk*t.w;
                }
            }
        }
        if (isb) {
            const int cb = c - AL;
            const int4*   bp  = (const int4*)(bconn + (nc * BRD + cb) * KBB);
            const float4* hp4 = (const float4*)(hebb_in + (size_t)((b * NCC + nc) * BRD + cb) * KBB);
            #pragma unroll
            for (int q = 0; q < 4; ++q) {
                int4 bi = bp[q];
                float4 hbt = hp4[q];
                int bis[4]   = {bi.x, bi.y, bi.z, bi.w};
                float hbs[4] = {hbt.x, hbt.y, hbt.z, hbt.w};
                #pragma unroll
                for (int kk = 0; kk < 4; ++kk) {
                    const int k   = q * 4 + kk;
                    const int idx = bis[kk];
                    const int nb  = idx >> 4;
                    const int ch  = AL + (idx & 15);
                    const float wk = fsig(ovb[k] + hbs[kk]);
                    const float4* np = (const float4*)(prev + (size_t)((b * NCC + nb) * CCH + ch) * DD);
                    #pragma unroll
                    for (int dq = 0; dq < 8; ++dq) {
                        float4 t = np[dq];
                        agg[dq*4+0] += wk*t.x; agg[dq*4+1] += wk*t.y;
                        agg[dq*4+2] += wk*t.z; agg[dq*4+3] += wk*t.w;
                    }
                }
            }
        }
        #pragma unroll
        for (int q = 0; q < 16; ++q) xs[16 + q] = packpair(agg[2*q], agg[2*q+1]);
    }

    // ---- state MLP + h_new
    uint32 hnp[16];
    {
        float delta[32];
        mlp2(xs, w1buf, w2buf, b1buf, b2buf, delta);
        const float sd = fsig(decayl);
        float* hrow = o_hnew + (size_t)r * DD;
        #pragma unroll
        for (int q = 0; q < 16; ++q) {
            float h0, h1;
            unpackpair(xs[q], h0, h1);
            const float t0 = sd * h0 + (1.0f - sd) * ftanhf(delta[2*q]);
            const float t1 = sd * h1 + (1.0f - sd) * ftanhf(delta[2*q+1]);
            hnp[q] = packpair(t0, t1);
            *(float2*)(hrow + 2*q) = make_float2(t0, t1);
        }
    }

    __syncthreads();
    stageW(tid, qw1, 96, qb1, qw2, qb2, w1buf, w2buf, b1buf, b2buf);
    __syncthreads();

    // ---- msg MLP: [h_new(32), agg(32), nid(32)]
    float macc[32];
    {
        uint32 xm[52];
        #pragma unroll
        for (int q = 0; q < 16; ++q) xm[q] = hnp[q];
        #pragma unroll
        for (int q = 0; q < 16; ++q) xm[16 + q] = xs[16 + q];
        const float4* npd = (const float4*)(nidp + (size_t)n * DD);
        #pragma unroll
        for (int q = 0; q < 8; ++q) {
            float4 t = npd[q];
            xm[32 + 2*q]     = packpair(t.x, t.y);
            xm[32 + 2*q + 1] = packpair(t.z, t.w);
        }
        xm[48] = xm[49] = xm[50] = xm[51] = 0u;
        mlp2(xm, w1buf, w2buf, b1buf, b2buf, macc);
        float4* mop = (float4*)(o_msg + (size_t)r * DD);
        #pragma unroll
        for (int q = 0; q < 8; ++q)
            mop[q] = make_float4(macc[q*4+0], macc[q*4+1], macc[q*4+2], macc[q*4+3]);
    }

    // ---- hebbian updates
    {
        const int4* cp = (const int4*)(conn + n * KK);
        #pragma unroll
        for (int q = 0; q < 4; ++q) {
            int4 ci = cp[q];
            int cis[4] = {ci.x, ci.y, ci.z, ci.w};
            float hres[4];
            #pragma unroll
            for (int kk = 0; kk < 4; ++kk) {
                const float4* np = (const float4*)(prev + (size_t)(cellbase + cis[kk]) * DD);
                float dot = 0.0f;
                #pragma unroll
                for (int dq = 0; dq < 8; ++dq) {
                    float4 t = np[dq];
                    dot += macc[dq*4+0]*t.x + macc[dq*4+1]*t.y
                         + macc[dq*4+2]*t.z + macc[dq*4+3]*t.w;
                }
                hres[kk] = 0.9f * hb[q*4+kk] + 0.003125f * dot;
            }
            *(float4*)(o_heb + (size_t)r * KK + q*4)
                = make_float4(hres[0], hres[1], hres[2], hres[3]);
        }
    }
    if (isb) {
        const int cb = c - AL;
        const int4*   bp  = (const int4*)(bconn + (nc * BRD + cb) * KBB);
        const float4* hp4 = (const float4*)(hebb_in + (size_t)((b * NCC + nc) * BRD + cb) * KBB);
        #pragma unroll
        for (int q = 0; q < 4; ++q) {
            int4 bi = bp[q];
            float4 hbt = hp4[q];
            int bis[4]   = {bi.x, bi.y, bi.z, bi.w};
            float hbs[4] = {hbt.x, hbt.y, hbt.z, hbt.w};
            float hres[4];
            #pragma unroll
            for (int kk = 0; kk < 4; ++kk) {
                const int idx = bis[kk];
                const int nb  = idx >> 4;
                const int ch  = AL + (idx & 15);
                const float4* np = (const float4*)(prev + (size_t)((b * NCC + nb) * CCH + ch) * DD);
                float dot = 0.0f;
                #pragma unroll
                for (int dq = 0; dq < 8; ++dq) {
                    float4 t = np[dq];
                    dot += macc[dq*4+0]*t.x + macc[dq*4+1]*t.y
                         + macc[dq*4+2]*t.z + macc[dq*4+3]*t.w;
                }
                hres[kk] = 0.9f * hbs[kk] + 0.003125f * dot;
            }
            *(float4*)(o_hebb + (size_t)((b * NCC + nc) * BRD + cb) * KBB + q*4)
                = make_float4(hres[0], hres[1], hres[2], hres[3]);
        }
    }
}

// ---------------------------------------------------------------------------
// Kernel C: readout = mean over channels [C-ALPHA, C) of msg -> (BS, NC*D)
// ---------------------------------------------------------------------------
__global__ __launch_bounds__(256) void kC(const float* __restrict__ msg,
                                          float* __restrict__ ro)
{
    const int t = blockIdx.x * 256 + threadIdx.x;
    const int b   = t >> 11;
    const int rem = t & 2047;
    const int nc  = rem >> 5;
    const int d   = rem & 31;
    const float* mp = msg + (size_t)((b * NCC + nc) * CCH + (CCH - AL)) * DD + d;
    float s = 0.0f;
    #pragma unroll
    for (int j = 0; j < 16; ++j) s += mp[j * DD];
    ro[t] = s * (1.0f / 16.0f);
}

extern "C" void kernel_launch(void* const* d_in, const int* in_sizes, int n_in,
                              void* d_out, int out_size, void* d_ws, size_t ws_size,
                              hipStream_t stream) {
    const float* x     = (const float*)d_in[0];
    const float* h     = (const float*)d_in[1];
    const float* prev  = (const float*)d_in[2];
    const float* dlog  = (const float*)d_in[3];
    const float* prim  = (const float*)d_in[4];
    const float* heb   = (const float*)d_in[5];
    const float* hebb  = (const float*)d_in[6];
    const float* sw1   = (const float*)d_in[7];
    const float* sb1   = (const float*)d_in[8];
    const float* sw2   = (const float*)d_in[9];
    const float* sb2   = (const float*)d_in[10];
    const float* qw1   = (const float*)d_in[11];
    const float* qb1   = (const float*)d_in[12];
    const float* qw2   = (const float*)d_in[13];
    const float* qb2   = (const float*)d_in[14];
    const float* mw1   = (const float*)d_in[15];
    const float* mb1   = (const float*)d_in[16];
    const float* mw2   = (const float*)d_in[17];
    const float* mb2   = (const float*)d_in[18];
    const float* nid   = (const float*)d_in[19];
    const int*   conn  = (const int*)d_in[20];
    const int*   bconn = (const int*)d_in[21];

    float* out   = (float*)d_out;
    float* ro    = out;                          // (8, 2048)
    float* hnew  = out + 16384;                  // (8,64,256,32)
    float* msg   = hnew + 4194304;               // (8,64,256,32)
    float* hebo  = msg + 4194304;                // (8,64,256,16)
    float* hebbo = hebo + 2097152;               // (8,64,16,16)
    float* ws    = (float*)d_ws;                 // 8*16384*68*4 = 35,651,584 B

    kA<<<NTOT / 8, 256, 0, stream>>>(x, h, dlog, prim, heb, nid, mw1, mb1, mw2, mb2, ws);
    kB<<<(BSZ * NTOT) / 256, 256, 0, stream>>>(x, h, prev, heb, hebb,
                                               sw1, sb1, sw2, sb2,
                                               qw1, qb1, qw2, qb2,
                                               nid, conn, bconn, ws,
                                               hnew, msg, hebo, hebbo);
    kC<<<64, 256, 0, stream>>>(msg, ro);
}